// Round 12
// baseline (1361.752 us; speedup 1.0000x reference)
//
#include <hip/hip_runtime.h>
#include <cstdint>
#include <cstddef>

typedef unsigned short u16;
typedef __attribute__((ext_vector_type(8))) short bf16x8;
typedef __attribute__((ext_vector_type(4))) float f32x4;
typedef unsigned int u32;
typedef __attribute__((address_space(1))) const u32 gu32;
typedef __attribute__((address_space(3))) u32 lu32;

__device__ __forceinline__ void gload_lds16(const void* g, void* l) {
    __builtin_amdgcn_global_load_lds((gu32*)g, (lu32*)l, 16, 0, 0);
}

__device__ __forceinline__ u16 f2bf(float v) {
    u32 u = __float_as_uint(v);
    return (u16)((u + 0x7fffu + ((u >> 16) & 1u)) >> 16);
}
__device__ __forceinline__ float bf2f(u16 h) { return __uint_as_float(((u32)h) << 16); }

__device__ __forceinline__ void split3(float f, u16& h1, u16& h2, u16& h3) {
    h1 = f2bf(f); float r = f - bf2f(h1);
    h2 = f2bf(r); r -= bf2f(h2);
    h3 = f2bf(r);
}

// 6-term emulated f32 product
__device__ __forceinline__ void mfma6(f32x4& c, bf16x8 a1, bf16x8 a2, bf16x8 a3,
                                      bf16x8 b1, bf16x8 b2, bf16x8 b3) {
    c = __builtin_amdgcn_mfma_f32_16x16x32_bf16(a1, b1, c, 0, 0, 0);
    c = __builtin_amdgcn_mfma_f32_16x16x32_bf16(a1, b2, c, 0, 0, 0);
    c = __builtin_amdgcn_mfma_f32_16x16x32_bf16(a2, b1, c, 0, 0, 0);
    c = __builtin_amdgcn_mfma_f32_16x16x32_bf16(a1, b3, c, 0, 0, 0);
    c = __builtin_amdgcn_mfma_f32_16x16x32_bf16(a3, b1, c, 0, 0, 0);
    c = __builtin_amdgcn_mfma_f32_16x16x32_bf16(a2, b2, c, 0, 0, 0);
}

// ---------------------------------------------------------------------------
// Activation prep (coalesced transpose): x (8,2048,I) f32 -> parity k8 planes
// [g][b][parity][1025][8].
// ---------------------------------------------------------------------------
__global__ __launch_bounds__(256)
void split_x8t(const float* __restrict__ x, u16* __restrict__ p0,
               size_t pstr, int I) {
    __shared__ u16 tl[12288];                 // [3][8][64][8]
    const int b = blockIdx.x / 33, blk = blockIdx.x - b * 33;
    const int o0 = blk * 64;
    const int nval = (o0 + 64 <= 2050) ? 64 : (2050 - o0);
    const int c0 = blockIdx.y << 6;
    const int tid = threadIdx.x;
    const int r = tid >> 2, c4 = tid & 3;

    if (r < nval) {
        int local = o0 + r;
        int parity = local >= 1025 ? 1 : 0;
        int idx = local - parity * 1025;
        int prow = 2 * idx + parity;
        bool pad = (prow == 0) || (prow == 2049);
        int s = pad ? 0 : (prow - 1);
        const float* src = x + (size_t)(b * 2048 + s) * I + c0;
#pragma unroll
        for (int k = 0; k < 4; k++) {
            int cf4 = c4 + k * 4;
            float4 v = make_float4(0.f, 0.f, 0.f, 0.f);
            if (!pad) v = *reinterpret_cast<const float4*>(src + cf4 * 4);
            float vals[4] = {v.x, v.y, v.z, v.w};
            int base = ((cf4 >> 1) * 64 + r) * 8 + (cf4 & 1) * 4;
#pragma unroll
            for (int q = 0; q < 4; q++) {
                u16 h1, h2, h3; split3(vals[q], h1, h2, h3);
                tl[base + q]        = h1;
                tl[4096 + base + q] = h2;
                tl[8192 + base + q] = h3;
            }
        }
    }
    __syncthreads();
#pragma unroll
    for (int e = tid; e < 1536; e += 256) {
        int p = e >> 9, rem = e & 511;
        int gs = rem >> 6, rr = rem & 63;
        if (rr < nval) {
            size_t dst = (size_t)p * pstr +
                         (size_t)((c0 >> 3) + gs) * 131200 +
                         (size_t)(b * 2050 + o0 + rr) * 8;
            *reinterpret_cast<bf16x8*>(&p0[dst]) =
                *reinterpret_cast<const bf16x8*>(&tl[p * 4096 + (gs * 64 + rr) * 8]);
        }
    }
}

// ---------------------------------------------------------------------------
// Generic row split (coalesced transpose): in (R,C) f32 -> plane[g][r][8].
// ---------------------------------------------------------------------------
__global__ __launch_bounds__(256)
void split_rows8t(const float* __restrict__ in, u16* __restrict__ p0,
                  size_t pstr, int R, int C) {
    __shared__ u16 tl[12288];
    const int r0 = blockIdx.x << 6;
    const int c0 = blockIdx.y << 6;
    const int tid = threadIdx.x;
    const int r = tid >> 2, c4 = tid & 3;
    const float* src = in + (size_t)(r0 + r) * C + c0;
#pragma unroll
    for (int k = 0; k < 4; k++) {
        int cf4 = c4 + k * 4;
        float4 v = *reinterpret_cast<const float4*>(src + cf4 * 4);
        float vals[4] = {v.x, v.y, v.z, v.w};
        int base = ((cf4 >> 1) * 64 + r) * 8 + (cf4 & 1) * 4;
#pragma unroll
        for (int q = 0; q < 4; q++) {
            u16 h1, h2, h3; split3(vals[q], h1, h2, h3);
            tl[base + q]        = h1;
            tl[4096 + base + q] = h2;
            tl[8192 + base + q] = h3;
        }
    }
    __syncthreads();
#pragma unroll
    for (int e = tid; e < 1536; e += 256) {
        int p = e >> 9, rem = e & 511;
        int gs = rem >> 6, rr = rem & 63;
        size_t dst = (size_t)p * pstr +
                     ((size_t)((c0 >> 3) + gs) * R + (r0 + rr)) * 8;
        *reinterpret_cast<bf16x8*>(&p0[dst]) =
            *reinterpret_cast<const bf16x8*>(&tl[p * 4096 + (gs * 64 + rr) * 8]);
    }
}

// ---------------------------------------------------------------------------
// Weight prep (coalesced transpose, TILE-MAJOR): w (O,I,4) f32 ->
// plane[ng][kg][NT][8], kg = kcv*G + i/8, ng = o/NT.  Grid: (O/64, I/64).
// ---------------------------------------------------------------------------
__global__ __launch_bounds__(256)
void split_weightT8m(const float* __restrict__ w, u16* __restrict__ p0,
                     size_t pstr, int I, int O, int NT) {
    __shared__ u16 tl[12288];
    const int o0 = blockIdx.x << 6;
    const int c0 = blockIdx.y << 6;
    const int G = I >> 3;
    const size_t SLAB = (size_t)4 * G * NT * 8;
    const int tid = threadIdx.x;
    const int r = tid >> 2, c4 = tid & 3;
    for (int kcv = 0; kcv < 4; kcv++) {
#pragma unroll
        for (int k = 0; k < 4; k++) {
            int cf4 = c4 + k * 4;
#pragma unroll
            for (int q = 0; q < 4; q++) {
                int i = c0 + cf4 * 4 + q;
                float f = w[((size_t)(o0 + r) * I + i) * 4 + kcv];
                u16 h1, h2, h3; split3(f, h1, h2, h3);
                int base = ((cf4 >> 1) * 64 + r) * 8 + (cf4 & 1) * 4 + q;
                tl[base]        = h1;
                tl[4096 + base] = h2;
                tl[8192 + base] = h3;
            }
        }
        __syncthreads();
        for (int e = tid; e < 1536; e += 256) {
            int p = e >> 9, rem = e & 511;
            int gs = rem >> 6, rr = rem & 63;
            int o = o0 + rr;
            int ng = o / NT, orr = o - ng * NT;
            int kg = kcv * G + (c0 >> 3) + gs;
            size_t dst = (size_t)p * pstr + (size_t)ng * SLAB +
                         (size_t)kg * NT * 8 + (size_t)orr * 8;
            *reinterpret_cast<bf16x8*>(&p0[dst]) =
                *reinterpret_cast<const bf16x8*>(&tl[p * 4096 + (gs * 64 + rr) * 8]);
        }
        __syncthreads();
    }
}

__global__ void cnorm_kernel(const float* __restrict__ cb, float* __restrict__ cn) {
    int w = threadIdx.x >> 6, lane = threadIdx.x & 63;
    int row = blockIdx.x * 4 + w;
    float4 v = *reinterpret_cast<const float4*>(&cb[(size_t)row * 256 + lane * 4]);
    float s = v.x * v.x + v.y * v.y + v.z * v.z + v.w * v.w;
#pragma unroll
    for (int off = 32; off; off >>= 1) s += __shfl_xor(s, off);
    if (lane == 0) cn[row] = s;
}

// ---------------------------------------------------------------------------
// Conv1d(k=4,s=2,p=1): 6-term MFMA, dbuf LDS (planes 1,2) + plane-3 direct
// with one-iteration REGISTER PREFETCH (ping-pong sets, unroll-2).
// Numerics bit-identical to round 11 (same values, same accumulation order).
// Final iter's prefetch/stage reads land inside workspace and are unused.
// ---------------------------------------------------------------------------
template<int TN>
__global__ __launch_bounds__(256, 2)
void conv_mfma8(const u16* __restrict__ xs, unsigned pstr_x,
                const u16* __restrict__ wt, unsigned pstr_w,
                const float* __restrict__ bias,
                u16* __restrict__ outp, unsigned pstr_o,
                int I, int O) {
    constexpr int FN = TN / 32;            // n-frags per wave (5 or 4)
    constexpr int NB = TN / 16;            // B loads per wave per iter (10 or 8)
    constexpr int BPLANE = 32 * TN;        // u16 per B plane per iter-slab
    constexpr int BUFE = 8192 + 2 * BPLANE;
    __shared__ u16 lds[2 * BUFE];
    const int m0 = blockIdx.x << 7;
    const int ny = blockIdx.y;
    const int n0 = ny * TN;
    const int tid = threadIdx.x, lane = tid & 63, wv = tid >> 6;
    const int wr = ((wv >> 1) & 1) << 6, wc = (wv & 1) * (TN / 2);
    const int fr = lane & 15, fkg = lane >> 4;
    const int b = m0 >> 10, t0 = m0 & 1023;
    const int G = I >> 3;
    const int SL = 131200;
    const int NIT = G, npt = G >> 2;
    const size_t SLAB = (size_t)4 * G * TN * 8;

    const u16* srcp[NB];
    int dsto[NB];
    const int nload = (wv < 2) ? 8 : NB;
    int inc;
    if (wv < 2) {
        inc = 4 * SL;
#pragma unroll
        for (int j = 0; j < NB; j++) {
            if (j < 8) {
                int kg = j >> 1, half = j & 1;
                int r = half * 64 + lane;
                srcp[j] = xs + (size_t)wv * pstr_x + (size_t)kg * SL +
                          (size_t)(b * 2050 + t0 + r) * 8;
                dsto[j] = wv * 4096 + j * 512;
            } else { srcp[j] = xs; dsto[j] = 0; }
        }
    } else {
        inc = BPLANE;
#pragma unroll
        for (int j = 0; j < NB; j++) {
            srcp[j] = wt + (size_t)(wv - 2) * pstr_w + (size_t)ny * SLAB +
                      j * 512 + lane * 8;
            dsto[j] = 8192 + (wv - 2) * BPLANE + j * 512;
        }
    }

    const u16* pa3 = xs + 2 * (size_t)pstr_x + (size_t)fkg * SL +
                     (size_t)(b * 2050 + t0 + wr + fr) * 8;
    const u16* pb3 = wt + 2 * (size_t)pstr_w + (size_t)ny * SLAB +
                     (size_t)fkg * (TN * 8) + (size_t)(wc + fr) * 8;

    f32x4 acc[4][FN];
#pragma unroll
    for (int i = 0; i < 4; i++)
#pragma unroll
        for (int j = 0; j < FN; j++) acc[i][j] = (f32x4){0.f, 0.f, 0.f, 0.f};

    int scnt = npt - 1, skcv = 0;
    int dcnt = npt, dkcv = 0;

    // prologue: stage iter 0 into buffer 0; preload direct set A (iter 0)
#pragma unroll
    for (int j = 0; j < NB; j++)
        if (j < nload) { gload_lds16(srcp[j], &lds[dsto[j]]); srcp[j] += inc; }
    bf16x8 daA[4], dbA[FN], daB[4], dbB[FN];
#pragma unroll
    for (int fm = 0; fm < 4; fm++)
        daA[fm] = *reinterpret_cast<const bf16x8*>(pa3 + fm * 128);
#pragma unroll
    for (int fn = 0; fn < FN; fn++)
        dbA[fn] = *reinterpret_cast<const bf16x8*>(pb3 + fn * 128);
    pa3 += 4 * SL;
    pb3 += BPLANE;
    if (--dcnt == 0) {
        pa3 += ((dkcv == 1) ? -8192 : 8200) - (int)pstr_x;
        dkcv++; dcnt = npt;
    }
    __syncthreads();

    auto subiter = [&](const u16* lbr, u16* lbw,
                       bf16x8 (&daU)[4], bf16x8 (&dbU)[FN],
                       bf16x8 (&daP)[4], bf16x8 (&dbP)[FN]) {
        // A) prefetch NEXT iter's direct plane-3 fragments (full phase of cover)
#pragma unroll
        for (int fm = 0; fm < 4; fm++)
            daP[fm] = *reinterpret_cast<const bf16x8*>(pa3 + fm * 128);
#pragma unroll
        for (int fn = 0; fn < FN; fn++)
            dbP[fn] = *reinterpret_cast<const bf16x8*>(pb3 + fn * 128);
        pa3 += 4 * SL;
        pb3 += BPLANE;
        if (--dcnt == 0) {
            pa3 += ((dkcv == 1) ? -8192 : 8200) - (int)pstr_x;
            dkcv++; dcnt = npt;
        }
        // B) stage next tile into the other buffer
#pragma unroll
        for (int j = 0; j < NB; j++)
            if (j < nload) {
                gload_lds16(srcp[j], lbw + dsto[j]);
                srcp[j] += inc;
            }
        if (wv < 2) {
            if (--scnt == 0) {
                int d = ((skcv == 1) ? -8192 : 8200) - (int)pstr_x;
#pragma unroll
                for (int j = 0; j < 8; j++) srcp[j] += d;
                skcv++; scnt = npt;
            }
        }
        // C) LDS -> register fragments of current buffer
        bf16x8 a1[4], a2[4], b1[FN], b2[FN];
#pragma unroll
        for (int fm = 0; fm < 4; fm++) {
            int aidx = fkg * 1024 + (wr + fm * 16 + fr) * 8;
            a1[fm] = *reinterpret_cast<const bf16x8*>(lbr + aidx);
            a2[fm] = *reinterpret_cast<const bf16x8*>(lbr + 4096 + aidx);
        }
#pragma unroll
        for (int fn = 0; fn < FN; fn++) {
            int bidx = 8192 + fkg * (TN * 8) + (wc + fn * 16 + fr) * 8;
            b1[fn] = *reinterpret_cast<const bf16x8*>(lbr + bidx);
            b2[fn] = *reinterpret_cast<const bf16x8*>(lbr + BPLANE + bidx);
        }
        // D) MFMA (uses current direct set)
        __builtin_amdgcn_s_setprio(1);
#pragma unroll
        for (int fm = 0; fm < 4; fm++)
#pragma unroll
            for (int fn = 0; fn < FN; fn++)
                mfma6(acc[fm][fn], a1[fm], a2[fm], daU[fm],
                      b1[fn], b2[fn], dbU[fn]);
        __builtin_amdgcn_s_setprio(0);
        __syncthreads();
    };

    for (int it = 0; it < NIT; it += 2) {
        subiter(lds, lds + BUFE, daA, dbA, daB, dbB);
        subiter(lds + BUFE, lds, daB, dbB, daA, dbA);
    }

    // ---- coalesced epilogue: per fm-slab, stage 3 planes in LDS, 16B stores
    u16 (*eld)[32][TN + 8] = (u16 (*)[32][TN + 8])lds;
    float bv[FN];
#pragma unroll
    for (int fn = 0; fn < FN; fn++) bv[fn] = bias[n0 + wc + fn * 16 + fr];
    const int srb = (wr >> 6) * 16 + fkg * 4;
#pragma unroll
    for (int fm = 0; fm < 4; fm++) {
#pragma unroll
        for (int fn = 0; fn < FN; fn++) {
            int cl = wc + fn * 16 + fr;
#pragma unroll
            for (int j = 0; j < 4; j++) {
                float f = acc[fm][fn][j] + bv[fn];
                u16 h1, h2, h3; split3(f, h1, h2, h3);
                eld[0][srb + j][cl] = h1;
                eld[1][srb + j][cl] = h2;
                eld[2][srb + j][cl] = h3;
            }
        }
        __syncthreads();
        for (int e = tid; e < 96 * (TN / 8); e += 256) {
            int g = e / 96, rem = e - g * 96;
            int p = rem >> 5, sr = rem & 31;
            bf16x8 vv = *reinterpret_cast<const bf16x8*>(&eld[p][sr][g * 8]);
            int rowg = m0 + ((sr >> 4) << 6) + fm * 16 + (sr & 15);
            size_t addr = (size_t)p * pstr_o +
                          (size_t)((n0 >> 3) + g) * 65536 + (size_t)rowg * 8;
            *reinterpret_cast<bf16x8*>(&outp[addr]) = vv;
        }
        __syncthreads();
    }
}

// ---------------------------------------------------------------------------
// Projection: 6-term MFMA over 3 k8 segments; z_e f32 + coalesced zpl planes.
// ---------------------------------------------------------------------------
__global__ __launch_bounds__(256, 3)
void proj_mfma5(const u16* __restrict__ sA, const u16* __restrict__ sB,
                const u16* __restrict__ sM, const u16* __restrict__ wp,
                const float* __restrict__ bias, float* __restrict__ z_e,
                u16* __restrict__ zpl) {
    __shared__ u16 lds[24576];
    const int m0 = blockIdx.x << 7;
    const int n0 = blockIdx.y << 7;
    const int tid = threadIdx.x, lane = tid & 63, wv = tid >> 6;
    const int wr = ((wv >> 1) & 1) << 6, wc = (wv & 1) << 6;
    const int fr = lane & 15, fkg = lane >> 4;

    const u16* srcp[12];
    int dsto[12];
#pragma unroll
    for (int j = 0; j < 12; j++) {
        int ii = wv * 12 + j;
        int tile = ii >> 3, sub = ii & 7;
        int kg = sub >> 1, half = sub & 1;
        int r = half * 64 + lane;
        if (tile >= 3)
            srcp[j] = wp + (size_t)(tile - 3) * 851968 + (size_t)kg * 2048 +
                      (size_t)(n0 + r) * 8;
        else
            srcp[j] = nullptr;
        dsto[j] = tile * 4096 + sub * 512;
    }

    f32x4 acc[4][4];
#pragma unroll
    for (int i = 0; i < 4; i++)
#pragma unroll
        for (int j = 0; j < 4; j++) acc[i][j] = (f32x4){0.f, 0.f, 0.f, 0.f};

    const u16* segp[3] = {sA, sB, sM};
    const int segG[3] = {160, 128, 128};
    const unsigned segP[3] = {10485760u, 8388608u, 8388608u};

    for (int seg = 0; seg < 3; seg++) {
        const u16* sp = segp[seg];
        const unsigned sps = segP[seg];
#pragma unroll
        for (int j = 0; j < 12; j++) {
            int ii = wv * 12 + j;
            int tile = ii >> 3, sub = ii & 7;
            int kg = sub >> 1, half = sub & 1;
            int r = half * 64 + lane;
            if (tile < 3)
                srcp[j] = sp + (size_t)tile * sps + (size_t)kg * 65536 +
                          (size_t)(m0 + r) * 8;
        }
        const int niter = segG[seg] >> 2;
        for (int it = 0; it < niter; it++) {
#pragma unroll
            for (int j = 0; j < 12; j++) {
                gload_lds16(srcp[j], &lds[dsto[j]]);
                int ii = wv * 12 + j;
                srcp[j] += (ii >> 3) < 3 ? 262144 : 8192;
            }
            __syncthreads();
            bf16x8 bfr[3][4];
#pragma unroll
            for (int p = 0; p < 3; p++)
#pragma unroll
                for (int fn = 0; fn < 4; fn++)
                    bfr[p][fn] = *reinterpret_cast<const bf16x8*>(
                        &lds[(3 + p) * 4096 + fkg * 1024 + (wc + fn * 16 + fr) * 8]);
            __builtin_amdgcn_s_setprio(1);
#pragma unroll
            for (int fm = 0; fm < 4; fm++) {
                int aidx = fkg * 1024 + (wr + fm * 16 + fr) * 8;
                bf16x8 a1 = *reinterpret_cast<const bf16x8*>(&lds[aidx]);
                bf16x8 a2 = *reinterpret_cast<const bf16x8*>(&lds[4096 + aidx]);
                bf16x8 a3 = *reinterpret_cast<const bf16x8*>(&lds[8192 + aidx]);
#pragma unroll
                for (int fn = 0; fn < 4; fn++)
                    mfma6(acc[fm][fn], a1, a2, a3, bfr[0][fn], bfr[1][fn], bfr[2][fn]);
            }
            __builtin_amdgcn_s_setprio(0);
            __syncthreads();
        }
    }
    u16 (*eld)[32][132] = (u16 (*)[32][132])lds;
    float bv[4];
#pragma unroll
    for (int fn = 0; fn < 4; fn++) bv[fn] = bias[n0 + wc + fn * 16 + fr];
    const int srb = (wr >> 6) * 16 + fkg * 4;
#pragma unroll
    for (int fm = 0; fm < 4; fm++) {
#pragma unroll
        for (int fn = 0; fn < 4; fn++) {
            int cl = wc + fn * 16 + fr;
            int col = n0 + cl;
#pragma unroll
            for (int j = 0; j < 4; j++) {
                float f = acc[fm][fn][j] + bv[fn];
                int rowg = m0 + wr + fm * 16 + fkg * 4 + j;
                z_e[(size_t)rowg * 256 + col] = f;
                u16 h1, h2, h3; split3(f, h1, h2, h3);
                eld[0][srb + j][cl] = h1;
                eld[1][srb + j][cl] = h2;
                eld[2][srb + j][cl] = h3;
            }
        }
        __syncthreads();
#pragma unroll
        for (int q = 0; q < 6; q++) {
            int e = q * 256 + tid;
            int g = e / 96, rem = e - g * 96;
            int p = rem >> 5, sr = rem & 31;
            bf16x8 vv = *reinterpret_cast<const bf16x8*>(&eld[p][sr][g * 8]);
            int rowg = m0 + ((sr >> 4) << 6) + fm * 16 + (sr & 15);
            size_t addr = (size_t)p * 2097152 +
                          (size_t)((n0 >> 3) + g) * 65536 + (size_t)rowg * 8;
            *reinterpret_cast<bf16x8*>(&zpl[addr]) = vv;
        }
        __syncthreads();
    }
}

// ---------------------------------------------------------------------------
// VQ: 6-term MFMA (K=256), dbuf LDS (planes 1,2) + plane-3 direct with
// one-iter register prefetch (unroll-2 ping-pong).  f64 compare + argmin.
// Bit-identical accumulation to round-11 vq_mfma5.
// ---------------------------------------------------------------------------
__global__ __launch_bounds__(256, 2)
void vq_mfma6(const u16* __restrict__ zpl, const u16* __restrict__ cbpl,
              const float* __restrict__ cn, double* __restrict__ pmin,
              int* __restrict__ pidx) {
    __shared__ __align__(16) char smem[65536];   // 2 x 32KB dbuf; epilogue 48KB
    u16* lds = (u16*)smem;
    const int m0 = blockIdx.x << 7;
    const int n0 = blockIdx.y << 7;
    const int tid = threadIdx.x, lane = tid & 63, wv = tid >> 6;
    const int wr = ((wv >> 1) & 1) << 6, wc = (wv & 1) << 6;
    const int fr = lane & 15, fkg = lane >> 4;

    const u16* srcp[8];
    int dsto[8];
    {
        const u16* bse = (wv < 2) ? (zpl + (size_t)wv * 2097152)
                                  : (cbpl + (size_t)(wv - 2) * 2097152);
        int r0 = (wv < 2) ? m0 : n0;
#pragma unroll
        for (int j = 0; j < 8; j++) {
            int kg = j >> 1, half = j & 1;
            srcp[j] = bse + (size_t)kg * 65536 + (size_t)(r0 + half * 64 + lane) * 8;
            dsto[j] = wv * 4096 + j * 512;
        }
    }
    const u16* pa3 = zpl + (size_t)2 * 2097152 + (size_t)fkg * 65536 +
                     (size_t)(m0 + wr + fr) * 8;
    const u16* pb3 = cbpl + (size_t)2 * 2097152 + (size_t)fkg * 65536 +
                     (size_t)(n0 + wc + fr) * 8;

    f32x4 acc[4][4];
#pragma unroll
    for (int i = 0; i < 4; i++)
#pragma unroll
        for (int j = 0; j < 4; j++) acc[i][j] = (f32x4){0.f, 0.f, 0.f, 0.f};

    // prologue: stage iter 0 + preload direct set A
#pragma unroll
    for (int j = 0; j < 8; j++) {
        gload_lds16(srcp[j], &lds[dsto[j]]);
        srcp[j] += 262144;
    }
    bf16x8 daA[4], dbA[4], daB[4], dbB[4];
#pragma unroll
    for (int fm = 0; fm < 4; fm++)
        daA[fm] = *reinterpret_cast<const bf16x8*>(pa3 + fm * 128);
#pragma unroll
    for (int fn = 0; fn < 4; fn++)
        dbA[fn] = *reinterpret_cast<const bf16x8*>(pb3 + fn * 128);
    pa3 += 262144;
    pb3 += 262144;
    __syncthreads();

    auto subiter = [&](const u16* lbr, u16* lbw,
                       bf16x8 (&daU)[4], bf16x8 (&dbU)[4],
                       bf16x8 (&daP)[4], bf16x8 (&dbP)[4]) {
#pragma unroll
        for (int fm = 0; fm < 4; fm++)
            daP[fm] = *reinterpret_cast<const bf16x8*>(pa3 + fm * 128);
#pragma unroll
        for (int fn = 0; fn < 4; fn++)
            dbP[fn] = *reinterpret_cast<const bf16x8*>(pb3 + fn * 128);
        pa3 += 262144;
        pb3 += 262144;
#pragma unroll
        for (int j = 0; j < 8; j++) {
            gload_lds16(srcp[j], lbw + dsto[j]);
            srcp[j] += 262144;
        }
        bf16x8 a1[4], a2[4], b1[4], b2[4];
#pragma unroll
        for (int fm = 0; fm < 4; fm++) {
            int aidx = fkg * 1024 + (wr + fm * 16 + fr) * 8;
            a1[fm] = *reinterpret_cast<const bf16x8*>(lbr + aidx);
            a2[fm] = *reinterpret_cast<const bf16x8*>(lbr + 4096 + aidx);
        }
#pragma unroll
        for (int fn = 0; fn < 4; fn++) {
            int bidx = fkg * 1024 + (wc + fn * 16 + fr) * 8;
            b1[fn] = *reinterpret_cast<const bf16x8*>(lbr + 8192 + bidx);
            b2[fn] = *reinterpret_cast<const bf16x8*>(lbr + 12288 + bidx);
        }
        __builtin_amdgcn_s_setprio(1);
#pragma unroll
        for (int fm = 0; fm < 4; fm++)
#pragma unroll
            for (int fn = 0; fn < 4; fn++)
                mfma6(acc[fm][fn], a1[fm], a2[fm], daU[fm],
                      b1[fn], b2[fn], dbU[fn]);
        __builtin_amdgcn_s_setprio(0);
        __syncthreads();
    };

    for (int it = 0; it < 8; it += 2) {
        subiter(lds, lds + 16384, daA, dbA, daB, dbB);
        subiter(lds + 16384, lds, daB, dbB, daA, dbA);
    }

    // ---- epilogue: per-row argmin, d = |c|^2 - 2 dot in f64 (LDS reused)
    double (*red_d)[32] = (double (*)[32])smem;
    int (*red_n)[32] = (int (*)[32])(smem + 32768);
#pragma unroll
    for (int fm = 0; fm < 4; fm++)
#pragma unroll
        for (int j = 0; j < 4; j++) {
            double best = 1e300; int bestn = 0x7fffffff;
#pragma unroll
            for (int fn = 0; fn < 4; fn++) {
                int gn = n0 + wc + fn * 16 + fr;
                double d = (double)cn[gn] - 2.0 * (double)acc[fm][fn][j];
                if (d < best || (d == best && gn < bestn)) { best = d; bestn = gn; }
            }
            int row = wr + fm * 16 + fkg * 4 + j;
            int cand = ((wv & 1) << 4) + fr;
            red_d[row][cand] = best; red_n[row][cand] = bestn;
        }
    __syncthreads();
    if (tid < 128) {
        double best = red_d[tid][0]; int bestn = red_n[tid][0];
#pragma unroll 4
        for (int k = 1; k < 32; k++) {
            double d = red_d[tid][k]; int n2 = red_n[tid][k];
            if (d < best || (d == best && n2 < bestn)) { best = d; bestn = n2; }
        }
        size_t idx = (size_t)(m0 + tid) * 64 + (n0 >> 7);
        pmin[idx] = best; pidx[idx] = bestn;
    }
}

// ---------------------------------------------------------------------------
__global__ void vq_finalize(const double* __restrict__ pmin, const int* __restrict__ pidx,
                            const float* __restrict__ z, const float* __restrict__ cb,
                            float* __restrict__ out, double* __restrict__ cpart) {
    int w = threadIdx.x >> 6, lane = threadIdx.x & 63;
    int m = blockIdx.x * 4 + w;
    double d = pmin[(size_t)m * 64 + lane];
    int n = pidx[(size_t)m * 64 + lane];
#pragma unroll
    for (int off = 32; off; off >>= 1) {
        double d2 = __shfl_xor(d, off);
        int n2 = __shfl_xor(n, off);
        if (d2 < d || (d2 == d && n2 < n)) { d = d2; n = n2; }
    }
    float4 cv = *reinterpret_cast<const float4*>(&cb[(size_t)n * 256 + lane * 4]);
    float4 zv = *reinterpret_cast<const float4*>(&z[(size_t)m * 256 + lane * 4]);
    *reinterpret_cast<float4*>(&out[(size_t)m * 256 + lane * 4]) = cv;
    float dx = zv.x - cv.x, dy = zv.y - cv.y, dz = zv.z - cv.z, dw = zv.w - cv.w;
    double s = (double)(dx * dx) + (double)(dy * dy) + (double)(dz * dz) + (double)(dw * dw);
#pragma unroll
    for (int off = 32; off; off >>= 1) s += __shfl_xor(s, off);
    if (lane == 0) {
        out[2097152 + m] = (float)n;
        cpart[m] = s;
    }
}

__global__ void vq_reduce(const double* __restrict__ cpart, float* __restrict__ out) {
    __shared__ double sm[256];
    double s = 0.0;
    for (int i = threadIdx.x; i < 8192; i += 256) s += cpart[i];
    sm[threadIdx.x] = s;
    __syncthreads();
    for (int off = 128; off; off >>= 1) {
        if ((int)threadIdx.x < off) sm[threadIdx.x] += sm[threadIdx.x + off];
        __syncthreads();
    }
    if (threadIdx.x == 0) out[2105344] = (float)(sm[0] / 2097152.0);
}

// ---------------------------------------------------------------------------
extern "C" void kernel_launch(void* const* d_in, const int* in_sizes, int n_in,
                              void* d_out, int out_size, void* d_ws, size_t ws_size,
                              hipStream_t stream) {
    (void)in_sizes; (void)n_in; (void)out_size; (void)ws_size;
    const float* whisper   = (const float*)d_in[0];
    const float* wavlm     = (const float*)d_in[1];
    const float* muq       = (const float*)d_in[2];
    const float* w_conv_w  = (const float*)d_in[3];
    const float* w_conv_b  = (const float*)d_in[4];
    const float* wl_conv_w = (const float*)d_in[5];
    const float* wl_conv_b = (const float*)d_in[6];
    const float* proj_w    = (const float*)d_in[7];
    const float* proj_b    = (const float*)d_in[8];
    const float* codebook  = (const float*)d_in[9];
    float* out = (float*)d_out;
    char* wsb = (char*)d_ws;

    // ---- workspace layout (bytes), same footprint as round 11 ----
    u16*   xsA   = (u16*)(wsb + 0);            // 3 planes, pstr 20,992,000 elems
    u16*   wtbA  = (u16*)(wsb + 125952000);    // 3 planes, pstr 6,553,600
    u16*   cApl  = (u16*)(wsb + 176259072);    // 3 planes, pstr 10,485,760
    u16*   xsB   = (u16*)(wsb + 0);            // pstr 16,793,600
    u16*   wtbB  = (u16*)(wsb + 100761600);    // pstr 4,194,304
    u16*   cBpl  = (u16*)(wsb + 125927424);    // pstr 8,388,608
    u16*   muqpl = (u16*)(wsb + 0);            // pstr 8,388,608
    u16*   wtpPl = (u16*)(wsb + 50331648);     // pstr 851,968
    float* z_e   = (float*)(wsb + 55443456);   // 8192*256 f32
    u16*   zpl   = (u16*)(wsb + 63832064);     // pstr 2,097,152
    u16*   cbpl  = (u16*)(wsb + 76414976);     // pstr 2,097,152
    float* cnorm = (float*)(wsb + 88997888);
    double* pmin = (double*)(wsb + 89030656);
    int*    pidx = (int*)(wsb + 93224960);
    double* cpart= (double*)(wsb + 95322112);

    // phase 1: whisper conv (TN=160 -> grid 64x8 = 512 blocks, perfect fill)
    split_x8t<<<dim3(264, 20), 256, 0, stream>>>(whisper, xsA, 20992000, 1280);
    split_weightT8m<<<dim3(20, 20), 256, 0, stream>>>(w_conv_w, wtbA, 6553600,
                                                      1280, 1280, 160);
    conv_mfma8<160><<<dim3(64, 8), 256, 0, stream>>>(xsA, 20992000, wtbA, 6553600,
                                                     w_conv_b, cApl, 10485760,
                                                     1280, 1280);
    // phase 2: wavlm conv (TN=128 -> grid 64x8 = 512 blocks)
    split_x8t<<<dim3(264, 16), 256, 0, stream>>>(wavlm, xsB, 16793600, 1024);
    split_weightT8m<<<dim3(16, 16), 256, 0, stream>>>(wl_conv_w, wtbB, 4194304,
                                                      1024, 1024, 128);
    conv_mfma8<128><<<dim3(64, 8), 256, 0, stream>>>(xsB, 16793600, wtbB, 4194304,
                                                     wl_conv_b, cBpl, 8388608,
                                                     1024, 1024);
    // phase 3: projection
    split_rows8t<<<dim3(128, 16), 256, 0, stream>>>(muq, muqpl, 8388608, 8192, 1024);
    split_rows8t<<<dim3(4, 52), 256, 0, stream>>>(proj_w, wtpPl, 851968, 256, 3328);
    proj_mfma5<<<dim3(64, 2), 256, 0, stream>>>(cApl, cBpl, muqpl, wtpPl, proj_b, z_e, zpl);
    // phase 4: VQ
    split_rows8t<<<dim3(128, 4), 256, 0, stream>>>(codebook, cbpl, 2097152, 8192, 256);
    cnorm_kernel<<<2048, 256, 0, stream>>>(codebook, cnorm);
    vq_mfma6<<<dim3(64, 64), 256, 0, stream>>>(zpl, cbpl, cnorm, pmin, pidx);
    vq_finalize<<<2048, 256, 0, stream>>>(pmin, pidx, z_e, codebook, out, cpart);
    vq_reduce<<<1, 256, 0, stream>>>(cpart, out);
}

// Round 13
// 1233.339 us; speedup vs baseline: 1.1041x; 1.1041x over previous
//
#include <hip/hip_runtime.h>
#include <cstdint>
#include <cstddef>

typedef unsigned short u16;
typedef __attribute__((ext_vector_type(8))) short bf16x8;
typedef __attribute__((ext_vector_type(4))) float f32x4;
typedef unsigned int u32;
typedef __attribute__((address_space(1))) const u32 gu32;
typedef __attribute__((address_space(3))) u32 lu32;

__device__ __forceinline__ void gload_lds16(const void* g, void* l) {
    __builtin_amdgcn_global_load_lds((gu32*)g, (lu32*)l, 16, 0, 0);
}

__device__ __forceinline__ u16 f2bf(float v) {
    u32 u = __float_as_uint(v);
    return (u16)((u + 0x7fffu + ((u >> 16) & 1u)) >> 16);
}
__device__ __forceinline__ float bf2f(u16 h) { return __uint_as_float(((u32)h) << 16); }

__device__ __forceinline__ void split3(float f, u16& h1, u16& h2, u16& h3) {
    h1 = f2bf(f); float r = f - bf2f(h1);
    h2 = f2bf(r); r -= bf2f(h2);
    h3 = f2bf(r);
}

// 6-term emulated f32 product
__device__ __forceinline__ void mfma6(f32x4& c, bf16x8 a1, bf16x8 a2, bf16x8 a3,
                                      bf16x8 b1, bf16x8 b2, bf16x8 b3) {
    c = __builtin_amdgcn_mfma_f32_16x16x32_bf16(a1, b1, c, 0, 0, 0);
    c = __builtin_amdgcn_mfma_f32_16x16x32_bf16(a1, b2, c, 0, 0, 0);
    c = __builtin_amdgcn_mfma_f32_16x16x32_bf16(a2, b1, c, 0, 0, 0);
    c = __builtin_amdgcn_mfma_f32_16x16x32_bf16(a1, b3, c, 0, 0, 0);
    c = __builtin_amdgcn_mfma_f32_16x16x32_bf16(a3, b1, c, 0, 0, 0);
    c = __builtin_amdgcn_mfma_f32_16x16x32_bf16(a2, b2, c, 0, 0, 0);
}

// ---------------------------------------------------------------------------
// Activation prep (coalesced transpose): x (8,2048,I) f32 -> parity k8 planes
// [g][b][parity][1025][8].
// ---------------------------------------------------------------------------
__global__ __launch_bounds__(256)
void split_x8t(const float* __restrict__ x, u16* __restrict__ p0,
               size_t pstr, int I) {
    __shared__ u16 tl[12288];                 // [3][8][64][8]
    const int b = blockIdx.x / 33, blk = blockIdx.x - b * 33;
    const int o0 = blk * 64;
    const int nval = (o0 + 64 <= 2050) ? 64 : (2050 - o0);
    const int c0 = blockIdx.y << 6;
    const int tid = threadIdx.x;
    const int r = tid >> 2, c4 = tid & 3;

    if (r < nval) {
        int local = o0 + r;
        int parity = local >= 1025 ? 1 : 0;
        int idx = local - parity * 1025;
        int prow = 2 * idx + parity;
        bool pad = (prow == 0) || (prow == 2049);
        int s = pad ? 0 : (prow - 1);
        const float* src = x + (size_t)(b * 2048 + s) * I + c0;
#pragma unroll
        for (int k = 0; k < 4; k++) {
            int cf4 = c4 + k * 4;
            float4 v = make_float4(0.f, 0.f, 0.f, 0.f);
            if (!pad) v = *reinterpret_cast<const float4*>(src + cf4 * 4);
            float vals[4] = {v.x, v.y, v.z, v.w};
            int base = ((cf4 >> 1) * 64 + r) * 8 + (cf4 & 1) * 4;
#pragma unroll
            for (int q = 0; q < 4; q++) {
                u16 h1, h2, h3; split3(vals[q], h1, h2, h3);
                tl[base + q]        = h1;
                tl[4096 + base + q] = h2;
                tl[8192 + base + q] = h3;
            }
        }
    }
    __syncthreads();
#pragma unroll
    for (int e = tid; e < 1536; e += 256) {
        int p = e >> 9, rem = e & 511;
        int gs = rem >> 6, rr = rem & 63;
        if (rr < nval) {
            size_t dst = (size_t)p * pstr +
                         (size_t)((c0 >> 3) + gs) * 131200 +
                         (size_t)(b * 2050 + o0 + rr) * 8;
            *reinterpret_cast<bf16x8*>(&p0[dst]) =
                *reinterpret_cast<const bf16x8*>(&tl[p * 4096 + (gs * 64 + rr) * 8]);
        }
    }
}

// ---------------------------------------------------------------------------
// Generic row split (coalesced transpose): in (R,C) f32 -> plane[g][r][8].
// ---------------------------------------------------------------------------
__global__ __launch_bounds__(256)
void split_rows8t(const float* __restrict__ in, u16* __restrict__ p0,
                  size_t pstr, int R, int C) {
    __shared__ u16 tl[12288];
    const int r0 = blockIdx.x << 6;
    const int c0 = blockIdx.y << 6;
    const int tid = threadIdx.x;
    const int r = tid >> 2, c4 = tid & 3;
    const float* src = in + (size_t)(r0 + r) * C + c0;
#pragma unroll
    for (int k = 0; k < 4; k++) {
        int cf4 = c4 + k * 4;
        float4 v = *reinterpret_cast<const float4*>(src + cf4 * 4);
        float vals[4] = {v.x, v.y, v.z, v.w};
        int base = ((cf4 >> 1) * 64 + r) * 8 + (cf4 & 1) * 4;
#pragma unroll
        for (int q = 0; q < 4; q++) {
            u16 h1, h2, h3; split3(vals[q], h1, h2, h3);
            tl[base + q]        = h1;
            tl[4096 + base + q] = h2;
            tl[8192 + base + q] = h3;
        }
    }
    __syncthreads();
#pragma unroll
    for (int e = tid; e < 1536; e += 256) {
        int p = e >> 9, rem = e & 511;
        int gs = rem >> 6, rr = rem & 63;
        size_t dst = (size_t)p * pstr +
                     ((size_t)((c0 >> 3) + gs) * R + (r0 + rr)) * 8;
        *reinterpret_cast<bf16x8*>(&p0[dst]) =
            *reinterpret_cast<const bf16x8*>(&tl[p * 4096 + (gs * 64 + rr) * 8]);
    }
}

// ---------------------------------------------------------------------------
// Weight prep (coalesced transpose, TILE-MAJOR): w (O,I,4) f32 ->
// plane[ng][kg][NT][8], kg = kcv*G + i/8, ng = o/NT.  Grid: (O/64, I/64).
// ---------------------------------------------------------------------------
__global__ __launch_bounds__(256)
void split_weightT8m(const float* __restrict__ w, u16* __restrict__ p0,
                     size_t pstr, int I, int O, int NT) {
    __shared__ u16 tl[12288];
    const int o0 = blockIdx.x << 6;
    const int c0 = blockIdx.y << 6;
    const int G = I >> 3;
    const size_t SLAB = (size_t)4 * G * NT * 8;
    const int tid = threadIdx.x;
    const int r = tid >> 2, c4 = tid & 3;
    for (int kcv = 0; kcv < 4; kcv++) {
#pragma unroll
        for (int k = 0; k < 4; k++) {
            int cf4 = c4 + k * 4;
#pragma unroll
            for (int q = 0; q < 4; q++) {
                int i = c0 + cf4 * 4 + q;
                float f = w[((size_t)(o0 + r) * I + i) * 4 + kcv];
                u16 h1, h2, h3; split3(f, h1, h2, h3);
                int base = ((cf4 >> 1) * 64 + r) * 8 + (cf4 & 1) * 4 + q;
                tl[base]        = h1;
                tl[4096 + base] = h2;
                tl[8192 + base] = h3;
            }
        }
        __syncthreads();
        for (int e = tid; e < 1536; e += 256) {
            int p = e >> 9, rem = e & 511;
            int gs = rem >> 6, rr = rem & 63;
            int o = o0 + rr;
            int ng = o / NT, orr = o - ng * NT;
            int kg = kcv * G + (c0 >> 3) + gs;
            size_t dst = (size_t)p * pstr + (size_t)ng * SLAB +
                         (size_t)kg * NT * 8 + (size_t)orr * 8;
            *reinterpret_cast<bf16x8*>(&p0[dst]) =
                *reinterpret_cast<const bf16x8*>(&tl[p * 4096 + (gs * 64 + rr) * 8]);
        }
        __syncthreads();
    }
}

__global__ void cnorm_kernel(const float* __restrict__ cb, float* __restrict__ cn) {
    int w = threadIdx.x >> 6, lane = threadIdx.x & 63;
    int row = blockIdx.x * 4 + w;
    float4 v = *reinterpret_cast<const float4*>(&cb[(size_t)row * 256 + lane * 4]);
    float s = v.x * v.x + v.y * v.y + v.z * v.z + v.w * v.w;
#pragma unroll
    for (int off = 32; off; off >>= 1) s += __shfl_xor(s, off);
    if (lane == 0) cn[row] = s;
}

// ---------------------------------------------------------------------------
// Conv1d(k=4,s=2,p=1): 6-term MFMA, dbuf LDS (planes 1,2) + plane-3 direct.
// Per iter: ds_read(cur) -> DIRECT plane-3 loads -> stage(next) -> MFMA -> sync.
// Direct loads issued BEFORE staging so MFMA's wait leaves staged loads
// in flight (counted vmcnt instead of full drain).
// ---------------------------------------------------------------------------
template<int TN>
__global__ __launch_bounds__(256, 2)
void conv_mfma7(const u16* __restrict__ xs, unsigned pstr_x,
                const u16* __restrict__ wt, unsigned pstr_w,
                const float* __restrict__ bias,
                u16* __restrict__ outp, unsigned pstr_o,
                int I, int O) {
    constexpr int FN = TN / 32;            // n-frags per wave (5 or 4)
    constexpr int NB = TN / 16;            // B loads per wave per iter (10 or 8)
    constexpr int BPLANE = 32 * TN;        // u16 per B plane per iter-slab
    constexpr int BUFE = 8192 + 2 * BPLANE;
    __shared__ u16 lds[2 * BUFE];
    const int m0 = blockIdx.x << 7;
    const int ny = blockIdx.y;
    const int n0 = ny * TN;
    const int tid = threadIdx.x, lane = tid & 63, wv = tid >> 6;
    const int wr = ((wv >> 1) & 1) << 6, wc = (wv & 1) * (TN / 2);
    const int fr = lane & 15, fkg = lane >> 4;
    const int b = m0 >> 10, t0 = m0 & 1023;
    const int G = I >> 3;
    const int SL = 131200;
    const int NIT = G, npt = G >> 2;
    const size_t SLAB = (size_t)4 * G * TN * 8;

    const u16* srcp[NB];
    int dsto[NB];
    const int nload = (wv < 2) ? 8 : NB;
    int inc;
    if (wv < 2) {
        inc = 4 * SL;
#pragma unroll
        for (int j = 0; j < NB; j++) {
            if (j < 8) {
                int kg = j >> 1, half = j & 1;
                int r = half * 64 + lane;
                srcp[j] = xs + (size_t)wv * pstr_x + (size_t)kg * SL +
                          (size_t)(b * 2050 + t0 + r) * 8;
                dsto[j] = wv * 4096 + j * 512;
            } else { srcp[j] = xs; dsto[j] = 0; }
        }
    } else {
        inc = BPLANE;
#pragma unroll
        for (int j = 0; j < NB; j++) {
            srcp[j] = wt + (size_t)(wv - 2) * pstr_w + (size_t)ny * SLAB +
                      j * 512 + lane * 8;
            dsto[j] = 8192 + (wv - 2) * BPLANE + j * 512;
        }
    }

    const u16* pa3 = xs + 2 * (size_t)pstr_x + (size_t)fkg * SL +
                     (size_t)(b * 2050 + t0 + wr + fr) * 8;
    const u16* pb3 = wt + 2 * (size_t)pstr_w + (size_t)ny * SLAB +
                     (size_t)fkg * (TN * 8) + (size_t)(wc + fr) * 8;

    f32x4 acc[4][FN];
#pragma unroll
    for (int i = 0; i < 4; i++)
#pragma unroll
        for (int j = 0; j < FN; j++) acc[i][j] = (f32x4){0.f, 0.f, 0.f, 0.f};

    // prologue: stage iter 0 into buffer 0
#pragma unroll
    for (int j = 0; j < NB; j++)
        if (j < nload) { gload_lds16(srcp[j], &lds[dsto[j]]); srcp[j] += inc; }
    __syncthreads();

    int scnt = npt - 1, skcv = 0;
    int dcnt = npt, dkcv = 0;
    int cur = 0;

    for (int it = 0; it < NIT; ++it) {
        // 1. LDS -> register fragments of current buffer
        const u16* lb = &lds[cur * BUFE];
        bf16x8 a1[4], a2[4], b1[FN], b2[FN];
#pragma unroll
        for (int fm = 0; fm < 4; fm++) {
            int aidx = fkg * 1024 + (wr + fm * 16 + fr) * 8;
            a1[fm] = *reinterpret_cast<const bf16x8*>(lb + aidx);
            a2[fm] = *reinterpret_cast<const bf16x8*>(lb + 4096 + aidx);
        }
#pragma unroll
        for (int fn = 0; fn < FN; fn++) {
            int bidx = 8192 + fkg * (TN * 8) + (wc + fn * 16 + fr) * 8;
            b1[fn] = *reinterpret_cast<const bf16x8*>(lb + bidx);
            b2[fn] = *reinterpret_cast<const bf16x8*>(lb + BPLANE + bidx);
        }
        // 2. direct plane-3 loads FIRST (completes while staging stays in flight)
        bf16x8 da3[4], db3[FN];
#pragma unroll
        for (int fm = 0; fm < 4; fm++)
            da3[fm] = *reinterpret_cast<const bf16x8*>(pa3 + fm * 128);
#pragma unroll
        for (int fn = 0; fn < FN; fn++)
            db3[fn] = *reinterpret_cast<const bf16x8*>(pb3 + fn * 128);
        pa3 += 4 * SL;
        pb3 += BPLANE;
        if (--dcnt == 0) {
            pa3 += ((dkcv == 1) ? -8192 : 8200) - (int)pstr_x;
            dkcv++; dcnt = npt;
        }
        // 3. stage next iter into other buffer (stays in flight across MFMA)
        if (it + 1 < NIT) {
#pragma unroll
            for (int j = 0; j < NB; j++)
                if (j < nload) {
                    gload_lds16(srcp[j], &lds[(cur ^ 1) * BUFE + dsto[j]]);
                    srcp[j] += inc;
                }
            if (wv < 2) {
                if (--scnt == 0) {
                    int d = ((skcv == 1) ? -8192 : 8200) - (int)pstr_x;
#pragma unroll
                    for (int j = 0; j < 8; j++) srcp[j] += d;
                    skcv++; scnt = npt;
                }
            }
        }
        // 4. MFMA
        __builtin_amdgcn_s_setprio(1);
#pragma unroll
        for (int fm = 0; fm < 4; fm++)
#pragma unroll
            for (int fn = 0; fn < FN; fn++)
                mfma6(acc[fm][fn], a1[fm], a2[fm], da3[fm],
                      b1[fn], b2[fn], db3[fn]);
        __builtin_amdgcn_s_setprio(0);
        __syncthreads();
        cur ^= 1;
    }

    // ---- coalesced epilogue: per fm-slab, stage 3 planes in LDS, 16B stores
    u16 (*eld)[32][TN + 8] = (u16 (*)[32][TN + 8])lds;
    float bv[FN];
#pragma unroll
    for (int fn = 0; fn < FN; fn++) bv[fn] = bias[n0 + wc + fn * 16 + fr];
    const int srb = (wr >> 6) * 16 + fkg * 4;
#pragma unroll
    for (int fm = 0; fm < 4; fm++) {
#pragma unroll
        for (int fn = 0; fn < FN; fn++) {
            int cl = wc + fn * 16 + fr;
#pragma unroll
            for (int j = 0; j < 4; j++) {
                float f = acc[fm][fn][j] + bv[fn];
                u16 h1, h2, h3; split3(f, h1, h2, h3);
                eld[0][srb + j][cl] = h1;
                eld[1][srb + j][cl] = h2;
                eld[2][srb + j][cl] = h3;
            }
        }
        __syncthreads();
        for (int e = tid; e < 96 * (TN / 8); e += 256) {
            int g = e / 96, rem = e - g * 96;
            int p = rem >> 5, sr = rem & 31;
            bf16x8 vv = *reinterpret_cast<const bf16x8*>(&eld[p][sr][g * 8]);
            int rowg = m0 + ((sr >> 4) << 6) + fm * 16 + (sr & 15);
            size_t addr = (size_t)p * pstr_o +
                          (size_t)((n0 >> 3) + g) * 65536 + (size_t)rowg * 8;
            *reinterpret_cast<bf16x8*>(&outp[addr]) = vv;
        }
        __syncthreads();
    }
}

// ---------------------------------------------------------------------------
// Projection: 6-term MFMA over 3 k8 segments; z_e f32 + coalesced zpl planes.
// ---------------------------------------------------------------------------
__global__ __launch_bounds__(256, 3)
void proj_mfma5(const u16* __restrict__ sA, const u16* __restrict__ sB,
                const u16* __restrict__ sM, const u16* __restrict__ wp,
                const float* __restrict__ bias, float* __restrict__ z_e,
                u16* __restrict__ zpl) {
    __shared__ u16 lds[24576];
    const int m0 = blockIdx.x << 7;
    const int n0 = blockIdx.y << 7;
    const int tid = threadIdx.x, lane = tid & 63, wv = tid >> 6;
    const int wr = ((wv >> 1) & 1) << 6, wc = (wv & 1) << 6;
    const int fr = lane & 15, fkg = lane >> 4;

    const u16* srcp[12];
    int dsto[12];
#pragma unroll
    for (int j = 0; j < 12; j++) {
        int ii = wv * 12 + j;
        int tile = ii >> 3, sub = ii & 7;
        int kg = sub >> 1, half = sub & 1;
        int r = half * 64 + lane;
        if (tile >= 3)
            srcp[j] = wp + (size_t)(tile - 3) * 851968 + (size_t)kg * 2048 +
                      (size_t)(n0 + r) * 8;
        else
            srcp[j] = nullptr;
        dsto[j] = tile * 4096 + sub * 512;
    }

    f32x4 acc[4][4];
#pragma unroll
    for (int i = 0; i < 4; i++)
#pragma unroll
        for (int j = 0; j < 4; j++) acc[i][j] = (f32x4){0.f, 0.f, 0.f, 0.f};

    const u16* segp[3] = {sA, sB, sM};
    const int segG[3] = {160, 128, 128};
    const unsigned segP[3] = {10485760u, 8388608u, 8388608u};

    for (int seg = 0; seg < 3; seg++) {
        const u16* sp = segp[seg];
        const unsigned sps = segP[seg];
#pragma unroll
        for (int j = 0; j < 12; j++) {
            int ii = wv * 12 + j;
            int tile = ii >> 3, sub = ii & 7;
            int kg = sub >> 1, half = sub & 1;
            int r = half * 64 + lane;
            if (tile < 3)
                srcp[j] = sp + (size_t)tile * sps + (size_t)kg * 65536 +
                          (size_t)(m0 + r) * 8;
        }
        const int niter = segG[seg] >> 2;
        for (int it = 0; it < niter; it++) {
#pragma unroll
            for (int j = 0; j < 12; j++) {
                gload_lds16(srcp[j], &lds[dsto[j]]);
                int ii = wv * 12 + j;
                srcp[j] += (ii >> 3) < 3 ? 262144 : 8192;
            }
            __syncthreads();
            bf16x8 bfr[3][4];
#pragma unroll
            for (int p = 0; p < 3; p++)
#pragma unroll
                for (int fn = 0; fn < 4; fn++)
                    bfr[p][fn] = *reinterpret_cast<const bf16x8*>(
                        &lds[(3 + p) * 4096 + fkg * 1024 + (wc + fn * 16 + fr) * 8]);
            __builtin_amdgcn_s_setprio(1);
#pragma unroll
            for (int fm = 0; fm < 4; fm++) {
                int aidx = fkg * 1024 + (wr + fm * 16 + fr) * 8;
                bf16x8 a1 = *reinterpret_cast<const bf16x8*>(&lds[aidx]);
                bf16x8 a2 = *reinterpret_cast<const bf16x8*>(&lds[4096 + aidx]);
                bf16x8 a3 = *reinterpret_cast<const bf16x8*>(&lds[8192 + aidx]);
#pragma unroll
                for (int fn = 0; fn < 4; fn++)
                    mfma6(acc[fm][fn], a1, a2, a3, bfr[0][fn], bfr[1][fn], bfr[2][fn]);
            }
            __builtin_amdgcn_s_setprio(0);
            __syncthreads();
        }
    }
    u16 (*eld)[32][132] = (u16 (*)[32][132])lds;
    float bv[4];
#pragma unroll
    for (int fn = 0; fn < 4; fn++) bv[fn] = bias[n0 + wc + fn * 16 + fr];
    const int srb = (wr >> 6) * 16 + fkg * 4;
#pragma unroll
    for (int fm = 0; fm < 4; fm++) {
#pragma unroll
        for (int fn = 0; fn < 4; fn++) {
            int cl = wc + fn * 16 + fr;
            int col = n0 + cl;
#pragma unroll
            for (int j = 0; j < 4; j++) {
                float f = acc[fm][fn][j] + bv[fn];
                int rowg = m0 + wr + fm * 16 + fkg * 4 + j;
                z_e[(size_t)rowg * 256 + col] = f;
                u16 h1, h2, h3; split3(f, h1, h2, h3);
                eld[0][srb + j][cl] = h1;
                eld[1][srb + j][cl] = h2;
                eld[2][srb + j][cl] = h3;
            }
        }
        __syncthreads();
#pragma unroll
        for (int q = 0; q < 6; q++) {
            int e = q * 256 + tid;
            int g = e / 96, rem = e - g * 96;
            int p = rem >> 5, sr = rem & 31;
            bf16x8 vv = *reinterpret_cast<const bf16x8*>(&eld[p][sr][g * 8]);
            int rowg = m0 + ((sr >> 4) << 6) + fm * 16 + (sr & 15);
            size_t addr = (size_t)p * 2097152 +
                          (size_t)((n0 >> 3) + g) * 65536 + (size_t)rowg * 8;
            *reinterpret_cast<bf16x8*>(&zpl[addr]) = vv;
        }
        __syncthreads();
    }
}

// ---------------------------------------------------------------------------
// VQ: 6-term MFMA (K=256), dbuf LDS (planes 1,2) + plane-3 direct (issued
// before staging), f64 compare + LDS argmin epilogue.  Grid (64,64).
// ---------------------------------------------------------------------------
__global__ __launch_bounds__(256, 2)
void vq_mfma5(const u16* __restrict__ zpl, const u16* __restrict__ cbpl,
              const float* __restrict__ cn, double* __restrict__ pmin,
              int* __restrict__ pidx) {
    __shared__ __align__(16) char smem[65536];   // 2 x 32KB dbuf; epilogue 48KB
    u16* lds = (u16*)smem;
    const int m0 = blockIdx.x << 7;
    const int n0 = blockIdx.y << 7;
    const int tid = threadIdx.x, lane = tid & 63, wv = tid >> 6;
    const int wr = ((wv >> 1) & 1) << 6, wc = (wv & 1) << 6;
    const int fr = lane & 15, fkg = lane >> 4;

    const u16* srcp[8];
    int dsto[8];
    {
        const u16* bse = (wv < 2) ? (zpl + (size_t)wv * 2097152)
                                  : (cbpl + (size_t)(wv - 2) * 2097152);
        int r0 = (wv < 2) ? m0 : n0;
#pragma unroll
        for (int j = 0; j < 8; j++) {
            int kg = j >> 1, half = j & 1;
            srcp[j] = bse + (size_t)kg * 65536 + (size_t)(r0 + half * 64 + lane) * 8;
            dsto[j] = wv * 4096 + j * 512;
        }
    }
    const u16* pa3 = zpl + (size_t)2 * 2097152 + (size_t)fkg * 65536 +
                     (size_t)(m0 + wr + fr) * 8;
    const u16* pb3 = cbpl + (size_t)2 * 2097152 + (size_t)fkg * 65536 +
                     (size_t)(n0 + wc + fr) * 8;

    f32x4 acc[4][4];
#pragma unroll
    for (int i = 0; i < 4; i++)
#pragma unroll
        for (int j = 0; j < 4; j++) acc[i][j] = (f32x4){0.f, 0.f, 0.f, 0.f};

    // prologue
#pragma unroll
    for (int j = 0; j < 8; j++) {
        gload_lds16(srcp[j], &lds[dsto[j]]);
        srcp[j] += 262144;
    }
    __syncthreads();

    int cur = 0;
    for (int it = 0; it < 8; ++it) {
        const u16* lb = &lds[cur * 16384];
        bf16x8 a1[4], a2[4], b1[4], b2[4];
#pragma unroll
        for (int fm = 0; fm < 4; fm++) {
            int aidx = fkg * 1024 + (wr + fm * 16 + fr) * 8;
            a1[fm] = *reinterpret_cast<const bf16x8*>(lb + aidx);
            a2[fm] = *reinterpret_cast<const bf16x8*>(lb + 4096 + aidx);
        }
#pragma unroll
        for (int fn = 0; fn < 4; fn++) {
            int bidx = fkg * 1024 + (wc + fn * 16 + fr) * 8;
            b1[fn] = *reinterpret_cast<const bf16x8*>(lb + 8192 + bidx);
            b2[fn] = *reinterpret_cast<const bf16x8*>(lb + 12288 + bidx);
        }
        // direct plane-3 loads BEFORE staging
        bf16x8 da3[4], db3[4];
#pragma unroll
        for (int fm = 0; fm < 4; fm++)
            da3[fm] = *reinterpret_cast<const bf16x8*>(pa3 + fm * 128);
#pragma unroll
        for (int fn = 0; fn < 4; fn++)
            db3[fn] = *reinterpret_cast<const bf16x8*>(pb3 + fn * 128);
        pa3 += 262144;
        pb3 += 262144;
        if (it + 1 < 8) {
#pragma unroll
            for (int j = 0; j < 8; j++) {
                gload_lds16(srcp[j], &lds[(cur ^ 1) * 16384 + dsto[j]]);
                srcp[j] += 262144;
            }
        }
        __builtin_amdgcn_s_setprio(1);
#pragma unroll
        for (int fm = 0; fm < 4; fm++)
#pragma unroll
            for (int fn = 0; fn < 4; fn++)
                mfma6(acc[fm][fn], a1[fm], a2[fm], da3[fm],
                      b1[fn], b2[fn], db3[fn]);
        __builtin_amdgcn_s_setprio(0);
        __syncthreads();
        cur ^= 1;
    }

    // ---- epilogue: per-row argmin, d = |c|^2 - 2 dot in f64 (LDS reused)
    double (*red_d)[32] = (double (*)[32])smem;
    int (*red_n)[32] = (int (*)[32])(smem + 32768);
#pragma unroll
    for (int fm = 0; fm < 4; fm++)
#pragma unroll
        for (int j = 0; j < 4; j++) {
            double best = 1e300; int bestn = 0x7fffffff;
#pragma unroll
            for (int fn = 0; fn < 4; fn++) {
                int gn = n0 + wc + fn * 16 + fr;
                double d = (double)cn[gn] - 2.0 * (double)acc[fm][fn][j];
                if (d < best || (d == best && gn < bestn)) { best = d; bestn = gn; }
            }
            int row = wr + fm * 16 + fkg * 4 + j;
            int cand = ((wv & 1) << 4) + fr;
            red_d[row][cand] = best; red_n[row][cand] = bestn;
        }
    __syncthreads();
    if (tid < 128) {
        double best = red_d[tid][0]; int bestn = red_n[tid][0];
#pragma unroll 4
        for (int k = 1; k < 32; k++) {
            double d = red_d[tid][k]; int n2 = red_n[tid][k];
            if (d < best || (d == best && n2 < bestn)) { best = d; bestn = n2; }
        }
        size_t idx = (size_t)(m0 + tid) * 64 + (n0 >> 7);
        pmin[idx] = best; pidx[idx] = bestn;
    }
}

// ---------------------------------------------------------------------------
__global__ void vq_finalize(const double* __restrict__ pmin, const int* __restrict__ pidx,
                            const float* __restrict__ z, const float* __restrict__ cb,
                            float* __restrict__ out, double* __restrict__ cpart) {
    int w = threadIdx.x >> 6, lane = threadIdx.x & 63;
    int m = blockIdx.x * 4 + w;
    double d = pmin[(size_t)m * 64 + lane];
    int n = pidx[(size_t)m * 64 + lane];
#pragma unroll
    for (int off = 32; off; off >>= 1) {
        double d2 = __shfl_xor(d, off);
        int n2 = __shfl_xor(n, off);
        if (d2 < d || (d2 == d && n2 < n)) { d = d2; n = n2; }
    }
    float4 cv = *reinterpret_cast<const float4*>(&cb[(size_t)n * 256 + lane * 4]);
    float4 zv = *reinterpret_cast<const float4*>(&z[(size_t)m * 256 + lane * 4]);
    *reinterpret_cast<float4*>(&out[(size_t)m * 256 + lane * 4]) = cv;
    float dx = zv.x - cv.x, dy = zv.y - cv.y, dz = zv.z - cv.z, dw = zv.w - cv.w;
    double s = (double)(dx * dx) + (double)(dy * dy) + (double)(dz * dz) + (double)(dw * dw);
#pragma unroll
    for (int off = 32; off; off >>= 1) s += __shfl_xor(s, off);
    if (lane == 0) {
        out[2097152 + m] = (float)n;
        cpart[m] = s;
    }
}

__global__ void vq_reduce(const double* __restrict__ cpart, float* __restrict__ out) {
    __shared__ double sm[256];
    double s = 0.0;
    for (int i = threadIdx.x; i < 8192; i += 256) s += cpart[i];
    sm[threadIdx.x] = s;
    __syncthreads();
    for (int off = 128; off; off >>= 1) {
        if ((int)threadIdx.x < off) sm[threadIdx.x] += sm[threadIdx.x + off];
        __syncthreads();
    }
    if (threadIdx.x == 0) out[2105344] = (float)(sm[0] / 2097152.0);
}

// ---------------------------------------------------------------------------
extern "C" void kernel_launch(void* const* d_in, const int* in_sizes, int n_in,
                              void* d_out, int out_size, void* d_ws, size_t ws_size,
                              hipStream_t stream) {
    (void)in_sizes; (void)n_in; (void)out_size; (void)ws_size;
    const float* whisper   = (const float*)d_in[0];
    const float* wavlm     = (const float*)d_in[1];
    const float* muq       = (const float*)d_in[2];
    const float* w_conv_w  = (const float*)d_in[3];
    const float* w_conv_b  = (const float*)d_in[4];
    const float* wl_conv_w = (const float*)d_in[5];
    const float* wl_conv_b = (const float*)d_in[6];
    const float* proj_w    = (const float*)d_in[7];
    const float* proj_b    = (const float*)d_in[8];
    const float* codebook  = (const float*)d_in[9];
    float* out = (float*)d_out;
    char* wsb = (char*)d_ws;

    // ---- workspace layout (bytes), same footprint as round 11 ----
    u16*   xsA   = (u16*)(wsb + 0);            // 3 planes, pstr 20,992,000 elems
    u16*   wtbA  = (u16*)(wsb + 125952000);    // 3 planes, pstr 6,553,600
    u16*   cApl  = (u16*)(wsb + 176259072);    // 3 planes, pstr 10,485,760
    u16*   xsB   = (u16*)(wsb + 0);            // pstr 16,793,600
    u16*   wtbB  = (u16*)(wsb + 100761600);    // pstr 4,194,304
    u16*   cBpl  = (u16*)(wsb + 125927424);    // pstr 8,388,608
    u16*   muqpl = (u16*)(wsb + 0);            // pstr 8,388,608
    u16*   wtpPl = (u16*)(wsb + 50331648);     // pstr 851,968
    float* z_e   = (float*)(wsb + 55443456);   // 8192*256 f32
    u16*   zpl   = (u16*)(wsb + 63832064);     // pstr 2,097,152
    u16*   cbpl  = (u16*)(wsb + 76414976);     // pstr 2,097,152
    float* cnorm = (float*)(wsb + 88997888);
    double* pmin = (double*)(wsb + 89030656);
    int*    pidx = (int*)(wsb + 93224960);
    double* cpart= (double*)(wsb + 95322112);

    // phase 1: whisper conv (TN=160 -> grid 64x8 = 512 blocks, perfect fill)
    split_x8t<<<dim3(264, 20), 256, 0, stream>>>(whisper, xsA, 20992000, 1280);
    split_weightT8m<<<dim3(20, 20), 256, 0, stream>>>(w_conv_w, wtbA, 6553600,
                                                      1280, 1280, 160);
    conv_mfma7<160><<<dim3(64, 8), 256, 0, stream>>>(xsA, 20992000, wtbA, 6553600,
                                                     w_conv_b, cApl, 10485760,
                                                     1280, 1280);
    // phase 2: wavlm conv (TN=128 -> grid 64x8 = 512 blocks)
    split_x8t<<<dim3(264, 16), 256, 0, stream>>>(wavlm, xsB, 16793600, 1024);
    split_weightT8m<<<dim3(16, 16), 256, 0, stream>>>(wl_conv_w, wtbB, 4194304,
                                                      1024, 1024, 128);
    conv_mfma7<128><<<dim3(64, 8), 256, 0, stream>>>(xsB, 16793600, wtbB, 4194304,
                                                     wl_conv_b, cBpl, 8388608,
                                                     1024, 1024);
    // phase 3: projection
    split_rows8t<<<dim3(128, 16), 256, 0, stream>>>(muq, muqpl, 8388608, 8192, 1024);
    split_rows8t<<<dim3(4, 52), 256, 0, stream>>>(proj_w, wtpPl, 851968, 256, 3328);
    proj_mfma5<<<dim3(64, 2), 256, 0, stream>>>(cApl, cBpl, muqpl, wtpPl, proj_b, z_e, zpl);
    // phase 4: VQ
    split_rows8t<<<dim3(128, 4), 256, 0, stream>>>(codebook, cbpl, 2097152, 8192, 256);
    cnorm_kernel<<<2048, 256, 0, stream>>>(codebook, cnorm);
    vq_mfma5<<<dim3(64, 64), 256, 0, stream>>>(zpl, cbpl, cnorm, pmin, pidx);
    vq_finalize<<<2048, 256, 0, stream>>>(pmin, pidx, z_e, codebook, out, cpart);
    vq_reduce<<<1, 256, 0, stream>>>(cpart, out);
}